// Round 7
// baseline (66.358 us; speedup 1.0000x reference)
//
#include <hip/hip_runtime.h>
#include <math.h>

#define HW   256
#define TR   16     // tile rows (owned)
#define TC   32     // tile cols (owned)
#define NBLK 8192   // 64 frames * 16 row-tiles * 8 col-tiles
#define BR   24     // hblur rows staged (TR + 2*4)
#define HC   36     // hblur/blur cols (TC + 2*2), multiple of 4
#define VR   20     // blur rows (TR + 2*2)
#define GR   18     // grad rows (TR + 2*1)
#define GC   34     // grad cols (TC + 2*1)
#define NHALO 100   // perimeter of GR x GC grid: 2*34 + 2*16
#define NG1  (BR * 9)   // 216 float4-groups in s_tmp  (<= 256: no loop)
#define NG2  (VR * 9)   // 180 float4-groups in s_blur (<= 256: no loop)

namespace {
// Gaussian(5, std=1) computed in float64 then cast, matching _gaussian_1d
constexpr double kE2  = 0.13533528323661269189;  // exp(-2)
constexpr double kE05 = 0.60653065971263342360;  // exp(-0.5)
constexpr double kSum = 1.0 + 2.0 * kE2 + 2.0 * kE05;
constexpr float G0f = (float)(kE2 / kSum);
constexpr float G1f = (float)(kE05 / kSum);
constexpr float G2f = (float)(1.0 / kSum);
constexpr float T1  = 0.41421356237309503f;   // tan(22.5 deg)
constexpr float T2  = 2.41421356237309503f;   // tan(67.5 deg)
__device__ __forceinline__ float fast_sqrtf(float x) {
    return __builtin_amdgcn_sqrtf(x);          // raw v_sqrt_f32 (1-2 ulp)
}
__device__ __forceinline__ int iclamp(int v, int lo, int hi) {
    return v < lo ? lo : (v > hi ? hi : v);
}
}

__global__ __launch_bounds__(256, 5)
void canny_tile_kernel(const float* __restrict__ imgA,
                       const float* __restrict__ imgB,
                       float* __restrict__ partials)
{
    // double-buffered pipeline stages
    __shared__ __align__(16) float s_tmp [2][BR * HC];
    __shared__ __align__(16) float s_blur[2][VR * HC];
    __shared__ float s_grad[2][GR * GC];
    __shared__ float s_red[4];

    const int tid  = threadIdx.x;
    const int bid  = blockIdx.x;
    const int n    = bid >> 7;           // frame 0..63
    const int tile = bid & 127;
    const int ty0  = (tile >> 3) * TR;   // 16 row-tiles
    const int tx0  = (tile & 7) * TC;    // 8 col-tiles

    const int ox  = tid & 31;            // owned column within tile
    const int oy0 = (tid >> 5) * 2;      // owned rows oy0, oy0+1

    // ---- hoisted staging geometry (loop-invariant across img & channel) ----
    const int  q9  = tid / 9;            // group row
    const int  c4  = (tid - 9 * q9) * 4; // group start col (elements)
    const int  stw = q9 * HC + c4;       // s_tmp / s_blur write index (float4)
    // A1 (tid < NG1): hblur row y1, first tap x0
    const bool a1on = (tid < NG1);
    const int  y1   = ty0 - 4 + q9;
    const bool y1ok = ((unsigned)y1 < HW);
    const int  x0   = tx0 - 4 + c4;
    const int  ga   = y1 * HW + iclamp(x0, 0, HW - 4);       // aligned, clamped
    const int  gb   = y1 * HW + iclamp(x0 + 4, 0, HW - 4);
    // A2 (tid < NG2): vblur row y2, output cols xb2..xb2+3
    const bool a2on = (tid < NG2);
    const int  y2   = ty0 - 2 + q9;
    const bool y2ok = ((unsigned)y2 < HW);
    const int  xb2  = tx0 - 2 + c4;
    const bool ok0 = ((unsigned)(xb2 + 0) < HW), ok1 = ((unsigned)(xb2 + 1) < HW);
    const bool ok2 = ((unsigned)(xb2 + 2) < HW), ok3 = ((unsigned)(xb2 + 3) < HW);
    // A3a: sobel window base (blur rows oy0+1 .. oy0+4, cols ox+1..ox+3)
    const int  b3  = (oy0 + 1) * HC + (ox + 1);
    const int  gw  = (oy0 + 1) * GC + (ox + 1);   // s_grad write/read center, k=0
    // halo element (r,cc) for threads < NHALO (perimeter of GR x GC)
    int h_r = 0, h_cc = 0;
    if (tid < 34)        { h_r = 0;            h_cc = tid; }
    else if (tid < 68)   { h_r = GR - 1;       h_cc = tid - 34; }
    else if (tid < 84)   { h_r = tid - 68 + 1; h_cc = 0; }
    else if (tid < NHALO){ h_r = tid - 84 + 1; h_cc = GC - 1; }
    const bool has_halo = (tid < NHALO);
    const bool h_in = ((unsigned)(ty0 - 1 + h_r) < HW) && ((unsigned)(tx0 - 1 + h_cc) < HW);
    const int  h_b  = h_r * HC + h_cc;            // s_blur read base for halo sobel
    const int  h_gw = h_r * GC + h_cc;            // s_grad write

    // ---- pipeline stage bodies (all args compile-time at call sites) ----
    auto A1 = [&](const float* __restrict__ plane, float* __restrict__ tmp) {
        if (a1on) {
            float4 o = make_float4(0.f, 0.f, 0.f, 0.f);
            if (y1ok) {
                const float4 a = *(const float4*)(plane + ga);
                const float4 b = *(const float4*)(plane + gb);
                o.x = G0f*a.x + G1f*a.y + G2f*a.z + G1f*a.w + G0f*b.x;
                o.y = G0f*a.y + G1f*a.z + G2f*a.w + G1f*b.x + G0f*b.y;
                o.z = G0f*a.z + G1f*a.w + G2f*b.x + G1f*b.y + G0f*b.z;
                o.w = G0f*a.w + G1f*b.x + G2f*b.y + G1f*b.z + G0f*b.w;
                if (x0 < 0) {                 // left image edge (x0 == -4)
                    o.x = G0f*a.x;
                    o.y = G1f*a.x + G0f*a.y;
                    o.z = G2f*a.x + G1f*a.y + G0f*a.z;
                    o.w = G1f*a.x + G2f*a.y + G1f*a.z + G0f*a.w;
                } else if (x0 > HW - 8) {     // right image edge (x0 == 252)
                    o.x = G0f*a.x + G1f*a.y + G2f*a.z + G1f*a.w;
                    o.y = G0f*a.y + G1f*a.z + G2f*a.w;
                    o.z = G0f*a.z + G1f*a.w;
                    o.w = G0f*a.w;
                }
            }
            *(float4*)&tmp[stw] = o;
        }
    };
    auto A2 = [&](const float* __restrict__ tmp, float* __restrict__ blur) {
        if (a2on) {
            float4 v = make_float4(0.f, 0.f, 0.f, 0.f);
            if (y2ok) {
                const float4 t0 = *(const float4*)&tmp[stw];
                const float4 t1 = *(const float4*)&tmp[stw + 1 * HC];
                const float4 t2 = *(const float4*)&tmp[stw + 2 * HC];
                const float4 t3 = *(const float4*)&tmp[stw + 3 * HC];
                const float4 t4 = *(const float4*)&tmp[stw + 4 * HC];
                v.x = ok0 ? (G0f*t0.x + G1f*t1.x + G2f*t2.x + G1f*t3.x + G0f*t4.x) : 0.f;
                v.y = ok1 ? (G0f*t0.y + G1f*t1.y + G2f*t2.y + G1f*t3.y + G0f*t4.y) : 0.f;
                v.z = ok2 ? (G0f*t0.z + G1f*t1.z + G2f*t2.z + G1f*t3.z + G0f*t4.z) : 0.f;
                v.w = ok3 ? (G0f*t0.w + G1f*t1.w + G2f*t2.w + G1f*t3.w + G0f*t4.w) : 0.f;
            }
            *(float4*)&blur[stw] = v;
        }
    };
    auto A3 = [&](const float* __restrict__ blur, float* __restrict__ grad,
                  float (&gxs)[2], float (&gys)[2], float (&gms)[2], float& hm) {
        // interior sobel via row-sum factoring (2 consecutive rows)
        float cd[4], rs[4];
        #pragma unroll
        for (int r = 0; r < 4; ++r) {
            const float* b = &blur[b3 + r * HC];
            const float bl = b[0], bc = b[1], br = b[2];
            cd[r] = bl - br;
            rs[r] = bl + 2.0f * bc + br;
        }
        #pragma unroll
        for (int k = 0; k < 2; ++k) {
            const float gx = cd[k] + 2.0f * cd[k + 1] + cd[k + 2];
            const float gy = rs[k] - rs[k + 2];
            gxs[k] += gx;
            gys[k] += gy;
            gms[k] += fast_sqrtf(gx * gx + gy * gy);
            grad[gw + k * GC] = gms[k];
        }
        // halo sobel (perimeter), one elem per thread
        if (has_halo) {
            float gmag = 0.0f;
            if (h_in) {
                const float* b = &blur[h_b];
                const float b00 = b[0],        b01 = b[1],          b02 = b[2];
                const float b10 = b[HC],                            b12 = b[HC + 2];
                const float b20 = b[2 * HC],   b21 = b[2 * HC + 1], b22 = b[2 * HC + 2];
                const float gx = (b00 + 2.0f * b10 + b20) - (b02 + 2.0f * b12 + b22);
                const float gy = (b00 + 2.0f * b01 + b02) - (b20 + 2.0f * b21 + b22);
                gmag = fast_sqrtf(gx * gx + gy * gy);
            }
            hm += gmag;
            grad[h_gw] = hm;
        }
    };
    auto NMS = [&](const float* __restrict__ grad,
                   const float (&gxs)[2], const float (&gys)[2], const float (&gms)[2],
                   float (&e)[2]) {
        #pragma unroll
        for (int k = 0; k < 2; ++k) {
            const float gc = gms[k];
            const float gx = gxs[k], gy = gys[k];
            const float ax = fabsf(gx), ay = fabsf(gy);
            int dy, dx;
            if (ay <= T1 * ax)      { dy = 0; dx = 1; }   // near 0/180 deg
            else if (ay >= T2 * ax) { dy = 1; dx = 0; }   // near +-90 deg
            else                    { dy = 1; dx = ((gx > 0.0f) == (gy > 0.0f)) ? 1 : -1; }
            const int ci = gw + k * GC;
            const float pos = gc - grad[ci + dy * GC + dx];
            const float neg = gc - grad[ci - dy * GC - dx];
            const float thin = (fminf(pos, neg) > 0.0f) ? gc : 0.0f;
            e[k] = (thin < 2.0f) ? 0.0f : thin;
        }
    };

    // per-image register state
    float gxs0[2] = {0.f, 0.f}, gys0[2] = {0.f, 0.f}, gms0[2] = {0.f, 0.f}, hm0 = 0.f;
    float gxs1[2] = {0.f, 0.f}, gys1[2] = {0.f, 0.f}, gms1[2] = {0.f, 0.f}, hm1 = 0.f;
    float e0[2], e1[2];

    const float* bA = imgA + (size_t)n * 3 * (HW * HW);
    const float* bB = imgB + (size_t)n * 3 * (HW * HW);

    // ---- 9-step software pipeline, 1 barrier per step ----
    // buffer parity: A1@s writes tmp[s&1]; A2@s reads tmp[(s-1)&1], writes
    // blur[(s-1)&1]; A3@s reads blur[(s-2)&1]. Writer/reader of every buffer
    // are always separated by exactly one barrier; never same-step.
    A1(bA,               s_tmp[0]);
    __syncthreads();                                                        // s0
    A1(bA + 1 * 65536,   s_tmp[1]);
    A2(s_tmp[0], s_blur[0]);
    __syncthreads();                                                        // s1
    A1(bA + 2 * 65536,   s_tmp[0]);
    A2(s_tmp[1], s_blur[1]);
    A3(s_blur[0], s_grad[0], gxs0, gys0, gms0, hm0);
    __syncthreads();                                                        // s2
    A1(bB,               s_tmp[1]);
    A2(s_tmp[0], s_blur[0]);
    A3(s_blur[1], s_grad[0], gxs0, gys0, gms0, hm0);
    __syncthreads();                                                        // s3
    A1(bB + 1 * 65536,   s_tmp[0]);
    A2(s_tmp[1], s_blur[1]);
    A3(s_blur[0], s_grad[0], gxs0, gys0, gms0, hm0);
    __syncthreads();                                                        // s4
    A1(bB + 2 * 65536,   s_tmp[1]);
    A2(s_tmp[0], s_blur[0]);
    A3(s_blur[1], s_grad[1], gxs1, gys1, gms1, hm1);
    NMS(s_grad[0], gxs0, gys0, gms0, e0);        // img0 edges (grad0 idle now)
    __syncthreads();                                                        // s5
    A2(s_tmp[1], s_blur[1]);
    A3(s_blur[0], s_grad[1], gxs1, gys1, gms1, hm1);
    __syncthreads();                                                        // s6
    A3(s_blur[1], s_grad[1], gxs1, gys1, gms1, hm1);
    __syncthreads();                                                        // s7
    NMS(s_grad[1], gxs1, gys1, gms1, e1);

    float acc = fabsf(e1[0] - e0[0]) + fabsf(e1[1] - e0[1]);

    // ---- deterministic block reduction
    #pragma unroll
    for (int off = 32; off > 0; off >>= 1) acc += __shfl_down(acc, off, 64);
    if ((tid & 63) == 0) s_red[tid >> 6] = acc;
    __syncthreads();                                                        // s8
    if (tid == 0) partials[bid] = (s_red[0] + s_red[1]) + (s_red[2] + s_red[3]);
}

__global__ void final_reduce_kernel(const float* __restrict__ partials,
                                    float* __restrict__ out)
{
    __shared__ float s_red[4];
    const int tid = threadIdx.x;  // 256 threads
    float v = 0.0f;
    #pragma unroll
    for (int j = 0; j < 32; ++j) v += partials[tid + 256 * j];
    #pragma unroll
    for (int off = 32; off > 0; off >>= 1) v += __shfl_down(v, off, 64);
    if ((tid & 63) == 0) s_red[tid >> 6] = v;
    __syncthreads();
    if (tid == 0)
        out[0] = ((s_red[0] + s_red[1]) + (s_red[2] + s_red[3])) * (1.0f / 4194304.0f);
}

extern "C" void kernel_launch(void* const* d_in, const int* in_sizes, int n_in,
                              void* d_out, int out_size, void* d_ws, size_t ws_size,
                              hipStream_t stream)
{
    const float* tgt     = (const float*)d_in[0];  // data_input  [4,16,3,256,256]
    const float* out_img = (const float*)d_in[1];  // model_output
    float* partials = (float*)d_ws;                // 8192 floats

    canny_tile_kernel<<<NBLK, 256, 0, stream>>>(out_img, tgt, partials);
    final_reduce_kernel<<<1, 256, 0, stream>>>(partials, (float*)d_out);
}

// Round 8
// 58.275 us; speedup vs baseline: 1.1387x; 1.1387x over previous
//
#include <hip/hip_runtime.h>
#include <math.h>

#define HW   256
#define TR   16     // tile rows (owned)
#define TC   32     // tile cols (owned)
#define NBLK 8192   // 64 frames * 16 row-tiles * 8 col-tiles
#define BR   24     // hblur rows staged (TR + 2*4)
#define HC   36     // hblur/blur cols (TC + 2*2), multiple of 4
#define VR   20     // blur rows (TR + 2*2)
#define GR   18     // grad rows (TR + 2*1)
#define GC   34     // grad cols (TC + 2*1) -- logical
#define GCP  35     // s_grad row stride (odd => decorrelated banks)
#define NHALO 100   // perimeter of GR x GC grid: 2*34 + 2*16
#define NG1  (BR * 9)   // 216 float4-groups in s_tmp  (<= 256: no loop)
#define NG2  (VR * 9)   // 180 float4-groups in s_blur (<= 256: no loop)

namespace {
// Gaussian(5, std=1) computed in float64 then cast, matching _gaussian_1d
constexpr double kE2  = 0.13533528323661269189;  // exp(-2)
constexpr double kE05 = 0.60653065971263342360;  // exp(-0.5)
constexpr double kSum = 1.0 + 2.0 * kE2 + 2.0 * kE05;
constexpr float G0f = (float)(kE2 / kSum);
constexpr float G1f = (float)(kE05 / kSum);
constexpr float G2f = (float)(1.0 / kSum);
constexpr float T1  = 0.41421356237309503f;   // tan(22.5 deg)
constexpr float T2  = 2.41421356237309503f;   // tan(67.5 deg)
__device__ __forceinline__ float fast_sqrtf(float x) {
    return __builtin_amdgcn_sqrtf(x);          // raw v_sqrt_f32 (1-2 ulp)
}
__device__ __forceinline__ int iclamp(int v, int lo, int hi) {
    return v < lo ? lo : (v > hi ? hi : v);
}
}

// EDGE=true: full bounds handling. EDGE=false: tile + all halos strictly
// inside the image -> every check folds away (branch-free fast path).
template<bool EDGE>
__device__ __forceinline__ float tile_body(
    const float* __restrict__ bA, const float* __restrict__ bB,
    const int tid, const int ty0, const int tx0,
    float* __restrict__ s_tmp, float* __restrict__ s_blur,
    float* __restrict__ s_grad)
{
    const int ox  = tid & 31;            // owned column within tile
    const int oy0 = (tid >> 5) * 2;      // owned rows oy0, oy0+1

    // ---- hoisted staging geometry (loop-invariant across img & channel) ----
    const int  q9  = tid / 9;            // group row
    const int  c4  = (tid - 9 * q9) * 4; // group start col (elements)
    const int  stw = q9 * HC + c4;       // s_tmp / s_blur write index (float4)
    const bool a1on = (tid < NG1);
    const int  y1   = ty0 - 4 + q9;
    const bool y1ok = !EDGE || ((unsigned)y1 < HW);
    const int  x0   = tx0 - 4 + c4;
    const int  ga   = y1 * HW + (EDGE ? iclamp(x0, 0, HW - 4) : x0);
    const int  gb   = y1 * HW + (EDGE ? iclamp(x0 + 4, 0, HW - 4) : x0 + 4);
    const bool a2on = (tid < NG2);
    const int  y2   = ty0 - 2 + q9;
    const bool y2ok = !EDGE || ((unsigned)y2 < HW);
    const int  xb2  = tx0 - 2 + c4;
    const bool ok0 = !EDGE || ((unsigned)(xb2 + 0) < HW);
    const bool ok1 = !EDGE || ((unsigned)(xb2 + 1) < HW);
    const bool ok2 = !EDGE || ((unsigned)(xb2 + 2) < HW);
    const bool ok3 = !EDGE || ((unsigned)(xb2 + 3) < HW);
    // A3a: sobel window base (blur rows oy0+1 .. oy0+4, cols ox+1..ox+3)
    const int  b3  = (oy0 + 1) * HC + (ox + 1);
    const int  gw  = (oy0 + 1) * GCP + (ox + 1);  // s_grad center, k=0
    // halo element (r,cc) for threads < NHALO (perimeter of GR x GC)
    int h_r = 0, h_cc = 0;
    if (tid < 34)        { h_r = 0;            h_cc = tid; }
    else if (tid < 68)   { h_r = GR - 1;       h_cc = tid - 34; }
    else if (tid < 84)   { h_r = tid - 68 + 1; h_cc = 0; }
    else if (tid < NHALO){ h_r = tid - 84 + 1; h_cc = GC - 1; }
    const bool has_halo = (tid < NHALO);
    const bool h_in = !EDGE || (((unsigned)(ty0 - 1 + h_r) < HW) &&
                                ((unsigned)(tx0 - 1 + h_cc) < HW));
    const int  h_b  = h_r * HC + h_cc;            // s_blur read base
    const int  h_gw = h_r * GCP + h_cc;           // s_grad write

    float e_first[2];
    float acc = 0.0f;

    for (int img = 0; img < 2; ++img) {
        const float* base = (img == 0) ? bA : bB;
        float gxs[2] = {0.f, 0.f}, gys[2] = {0.f, 0.f}, gms[2] = {0.f, 0.f};
        float hmag = 0.0f;

        for (int c = 0; c < 3; ++c) {
            const float* plane = base + c * (HW * HW);

            // ---- A1: horizontal 5-tap gaussian, 4 outputs/thread -> s_tmp
            if (a1on) {
                float4 o = make_float4(0.f, 0.f, 0.f, 0.f);
                if (y1ok) {
                    const float4 a = *(const float4*)(plane + ga);
                    const float4 b = *(const float4*)(plane + gb);
                    o.x = G0f*a.x + G1f*a.y + G2f*a.z + G1f*a.w + G0f*b.x;
                    o.y = G0f*a.y + G1f*a.z + G2f*a.w + G1f*b.x + G0f*b.y;
                    o.z = G0f*a.z + G1f*a.w + G2f*b.x + G1f*b.y + G0f*b.z;
                    o.w = G0f*a.w + G1f*b.x + G2f*b.y + G1f*b.z + G0f*b.w;
                    if (EDGE) {
                        if (x0 < 0) {             // left image edge (x0 == -4)
                            o.x = G0f*a.x;
                            o.y = G1f*a.x + G0f*a.y;
                            o.z = G2f*a.x + G1f*a.y + G0f*a.z;
                            o.w = G1f*a.x + G2f*a.y + G1f*a.z + G0f*a.w;
                        } else if (x0 > HW - 8) { // right image edge (x0 == 252)
                            o.x = G0f*a.x + G1f*a.y + G2f*a.z + G1f*a.w;
                            o.y = G0f*a.y + G1f*a.z + G2f*a.w;
                            o.z = G0f*a.z + G1f*a.w;
                            o.w = G0f*a.w;
                        }
                    }
                }
                *(float4*)&s_tmp[stw] = o;
            }
            __syncthreads();

            // ---- A2: vertical 5-tap gaussian, 4 outputs/thread -> s_blur
            // Sobel zero-pads BLUR, so blur outside the image must be exactly 0.
            if (a2on) {
                float4 v = make_float4(0.f, 0.f, 0.f, 0.f);
                if (y2ok) {
                    const float4 t0 = *(const float4*)&s_tmp[stw];
                    const float4 t1 = *(const float4*)&s_tmp[stw + 1 * HC];
                    const float4 t2 = *(const float4*)&s_tmp[stw + 2 * HC];
                    const float4 t3 = *(const float4*)&s_tmp[stw + 3 * HC];
                    const float4 t4 = *(const float4*)&s_tmp[stw + 4 * HC];
                    v.x = ok0 ? (G0f*t0.x + G1f*t1.x + G2f*t2.x + G1f*t3.x + G0f*t4.x) : 0.f;
                    v.y = ok1 ? (G0f*t0.y + G1f*t1.y + G2f*t2.y + G1f*t3.y + G0f*t4.y) : 0.f;
                    v.z = ok2 ? (G0f*t0.z + G1f*t1.z + G2f*t2.z + G1f*t3.z + G0f*t4.z) : 0.f;
                    v.w = ok3 ? (G0f*t0.w + G1f*t1.w + G2f*t2.w + G1f*t3.w + G0f*t4.w) : 0.f;
                }
                *(float4*)&s_blur[stw] = v;
            }
            __syncthreads();

            // ---- A3a: interior sobel via row-sum factoring (2 consecutive rows)
            {
                float cd[4], rs[4];
                #pragma unroll
                for (int r = 0; r < 4; ++r) {
                    const float* b = &s_blur[b3 + r * HC];
                    const float bl = b[0], bc = b[1], br = b[2];
                    cd[r] = bl - br;
                    rs[r] = bl + 2.0f * bc + br;
                }
                #pragma unroll
                for (int k = 0; k < 2; ++k) {
                    const float gx = cd[k] + 2.0f * cd[k + 1] + cd[k + 2];
                    const float gy = rs[k] - rs[k + 2];
                    gxs[k] += gx;
                    gys[k] += gy;
                    gms[k] += fast_sqrtf(gx * gx + gy * gy);
                    s_grad[gw + k * GCP] = gms[k];
                }
            }

            // ---- A3b: halo sobel (perimeter of GR x GC), one elem per thread
            if (has_halo) {
                float gmag = 0.0f;
                if (h_in) {
                    const float* b = &s_blur[h_b];
                    const float b00 = b[0],        b01 = b[1],          b02 = b[2];
                    const float b10 = b[HC],                            b12 = b[HC + 2];
                    const float b20 = b[2 * HC],   b21 = b[2 * HC + 1], b22 = b[2 * HC + 2];
                    const float gx = (b00 + 2.0f * b10 + b20) - (b02 + 2.0f * b12 + b22);
                    const float gy = (b00 + 2.0f * b01 + b02) - (b20 + 2.0f * b21 + b22);
                    gmag = fast_sqrtf(gx * gx + gy * gy);
                }
                hmag += gmag;
                s_grad[h_gw] = hmag;
            }
            // no sync here: next A1 writes only s_tmp, whose readers (A2) are
            // fenced by the post-A2 sync; s_blur readers (A3) complete before
            // any thread passes the next post-A1 sync.
        }
        __syncthreads();  // s_grad complete for all channels

        // ---- Phase B: axis-based NMS + threshold at owned pixels
        #pragma unroll
        for (int k = 0; k < 2; ++k) {
            const float gc = gms[k];
            const float gx = gxs[k], gy = gys[k];
            const float ax = fabsf(gx), ay = fabsf(gy);
            int dy, dx;
            if (ay <= T1 * ax)      { dy = 0; dx = 1; }   // near 0/180 deg
            else if (ay >= T2 * ax) { dy = 1; dx = 0; }   // near +-90 deg
            else                    { dy = 1; dx = ((gx > 0.0f) == (gy > 0.0f)) ? 1 : -1; }
            const int ci = gw + k * GCP;
            const float pos = gc - s_grad[ci + dy * GCP + dx];
            const float neg = gc - s_grad[ci - dy * GCP - dx];
            const float thin = (fminf(pos, neg) > 0.0f) ? gc : 0.0f;
            const float e    = (thin < 2.0f) ? 0.0f : thin;
            if (img == 0) e_first[k] = e;
            else          acc += fabsf(e - e_first[k]);
        }
        __syncthreads();  // s_grad reused by next image (writes fenced anyway)
    }
    return acc;
}

__global__ __launch_bounds__(256, 8)
void canny_tile_kernel(const float* __restrict__ imgA,
                       const float* __restrict__ imgB,
                       float* __restrict__ partials)
{
    __shared__ __align__(16) float s_tmp[BR * HC];   // horizontal gaussian
    __shared__ __align__(16) float s_blur[VR * HC];  // full blur
    __shared__ float s_grad[GR * GCP];               // channel-summed |grad| (padded stride)
    __shared__ float s_red[4];

    const int tid = threadIdx.x;
    // XCD-chunked bijective swizzle: xcd = blockIdx % 8 gets logical tiles
    // [xcd*1024, (xcd+1)*1024) -> neighbor tiles / same frame share an L2.
    const int bid = blockIdx.x;
    const int lg  = (bid & 7) * (NBLK / 8) + (bid >> 3);
    const int n    = lg >> 7;            // frame 0..63
    const int tile = lg & 127;
    const int rt   = tile >> 3;          // row-tile 0..15
    const int ct   = tile & 7;           // col-tile 0..7
    const int ty0  = rt * TR;
    const int tx0  = ct * TC;

    const float* bA = imgA + (size_t)n * 3 * (HW * HW);
    const float* bB = imgB + (size_t)n * 3 * (HW * HW);

    // interior: all staged rows/cols strictly inside the image
    // rows: ty0-4 >= 0 && ty0+19 <= 255 -> rt in [1,14]
    // cols: tx0-4 >= 0 && tx0+35 <= 255 -> ct in [1,6]
    const bool interior = (rt >= 1) && (rt <= 14) && (ct >= 1) && (ct <= 6);

    float acc;
    if (interior) acc = tile_body<false>(bA, bB, tid, ty0, tx0, s_tmp, s_blur, s_grad);
    else          acc = tile_body<true >(bA, bB, tid, ty0, tx0, s_tmp, s_blur, s_grad);

    // ---- deterministic block reduction
    #pragma unroll
    for (int off = 32; off > 0; off >>= 1) acc += __shfl_down(acc, off, 64);
    if ((tid & 63) == 0) s_red[tid >> 6] = acc;
    __syncthreads();
    if (tid == 0) partials[bid] = (s_red[0] + s_red[1]) + (s_red[2] + s_red[3]);
}

__global__ void final_reduce_kernel(const float* __restrict__ partials,
                                    float* __restrict__ out)
{
    __shared__ float s_red[16];
    const int tid = threadIdx.x;  // 1024 threads
    const float4 a = *(const float4*)&partials[4 * tid];
    const float4 b = *(const float4*)&partials[4 * tid + 4096];
    float v = ((a.x + a.y) + (a.z + a.w)) + ((b.x + b.y) + (b.z + b.w));
    #pragma unroll
    for (int off = 32; off > 0; off >>= 1) v += __shfl_down(v, off, 64);
    if ((tid & 63) == 0) s_red[tid >> 6] = v;
    __syncthreads();
    if (tid == 0) {
        float s = 0.0f;
        #pragma unroll
        for (int j = 0; j < 16; ++j) s += s_red[j];
        out[0] = s * (1.0f / 4194304.0f);
    }
}

extern "C" void kernel_launch(void* const* d_in, const int* in_sizes, int n_in,
                              void* d_out, int out_size, void* d_ws, size_t ws_size,
                              hipStream_t stream)
{
    const float* tgt     = (const float*)d_in[0];  // data_input  [4,16,3,256,256]
    const float* out_img = (const float*)d_in[1];  // model_output
    float* partials = (float*)d_ws;                // 8192 floats

    canny_tile_kernel<<<NBLK, 256, 0, stream>>>(out_img, tgt, partials);
    final_reduce_kernel<<<1, 1024, 0, stream>>>(partials, (float*)d_out);
}

// Round 9
// 47.060 us; speedup vs baseline: 1.4101x; 1.2383x over previous
//
#include <hip/hip_runtime.h>
#include <math.h>

#define HW   256
#define TR   16     // tile rows (owned)
#define TC   32     // tile cols (owned)
#define NBLK 8192   // 64 frames * 16 row-tiles * 8 col-tiles
#define BR   24     // hblur rows staged (TR + 2*4)
#define HC   36     // hblur/blur cols (TC + 2*2), multiple of 4
#define VR   20     // blur rows (TR + 2*2)
#define GR   18     // grad rows (TR + 2*1)
#define GC   34     // grad cols (TC + 2*1) -- logical
#define GCP  35     // s_grad row stride (odd => decorrelated banks)
#define NHALO 100   // perimeter of GR x GC grid: 2*34 + 2*16
#define NG1  (BR * 9)   // 216 float4-groups in s_tmp  (<= 256: no loop)
#define NG2  (VR * 9)   // 180 float4-groups in s_blur (<= 256: no loop)

typedef float f32x2 __attribute__((ext_vector_type(2)));

namespace {
// Gaussian(5, std=1) computed in float64 then cast, matching _gaussian_1d
constexpr double kE2  = 0.13533528323661269189;  // exp(-2)
constexpr double kE05 = 0.60653065971263342360;  // exp(-0.5)
constexpr double kSum = 1.0 + 2.0 * kE2 + 2.0 * kE05;
constexpr float G0f = (float)(kE2 / kSum);
constexpr float G1f = (float)(kE05 / kSum);
constexpr float G2f = (float)(1.0 / kSum);
constexpr float T1  = 0.41421356237309503f;   // tan(22.5 deg)
constexpr float T2  = 2.41421356237309503f;   // tan(67.5 deg)
__device__ __forceinline__ float fast_sqrtf(float x) {
    return __builtin_amdgcn_sqrtf(x);          // raw v_sqrt_f32 (1-2 ulp)
}
__device__ __forceinline__ int iclamp(int v, int lo, int hi) {
    return v < lo ? lo : (v > hi ? hi : v);
}
__device__ __forceinline__ f32x2 mk2(float x, float y) {
    f32x2 r; r.x = x; r.y = y; return r;
}
}

// EDGE=true: full bounds handling. EDGE=false: tile + all halos strictly
// inside the image -> every check folds away (branch-free fast path).
template<bool EDGE>
__device__ __forceinline__ float tile_body(
    const float* __restrict__ bA, const float* __restrict__ bB,
    const int tid, const int ty0, const int tx0,
    float* __restrict__ s_tmp, float* __restrict__ s_blur,
    float* __restrict__ s_grad)
{
    const int ox  = tid & 31;            // owned column within tile
    const int oy0 = (tid >> 5) * 2;      // owned rows oy0, oy0+1

    // packed gaussian coefficients (splat; compiler hoists to regs)
    const f32x2 g0p = mk2(G0f, G0f), g1p = mk2(G1f, G1f), g2p = mk2(G2f, G2f);

    // ---- hoisted staging geometry (loop-invariant across img & channel) ----
    const int  q9  = tid / 9;            // group row
    const int  c4  = (tid - 9 * q9) * 4; // group start col (elements)
    const int  stw = q9 * HC + c4;       // s_tmp / s_blur write index (float4)
    const bool a1on = (tid < NG1);
    const int  y1   = ty0 - 4 + q9;
    const bool y1ok = !EDGE || ((unsigned)y1 < HW);
    const int  x0   = tx0 - 4 + c4;
    const int  ga   = y1 * HW + (EDGE ? iclamp(x0, 0, HW - 4) : x0);
    const int  gb   = y1 * HW + (EDGE ? iclamp(x0 + 4, 0, HW - 4) : x0 + 4);
    const bool a2on = (tid < NG2);
    const int  y2   = ty0 - 2 + q9;
    const bool y2ok = !EDGE || ((unsigned)y2 < HW);
    const int  xb2  = tx0 - 2 + c4;
    const bool ok0 = !EDGE || ((unsigned)(xb2 + 0) < HW);
    const bool ok1 = !EDGE || ((unsigned)(xb2 + 1) < HW);
    const bool ok2 = !EDGE || ((unsigned)(xb2 + 2) < HW);
    const bool ok3 = !EDGE || ((unsigned)(xb2 + 3) < HW);
    // A3a: sobel window base (blur rows oy0+1 .. oy0+4, cols ox+1..ox+3)
    const int  b3  = (oy0 + 1) * HC + (ox + 1);
    const int  gw  = (oy0 + 1) * GCP + (ox + 1);  // s_grad center, k=0
    // halo element (r,cc) for threads < NHALO (perimeter of GR x GC)
    int h_r = 0, h_cc = 0;
    if (tid < 34)        { h_r = 0;            h_cc = tid; }
    else if (tid < 68)   { h_r = GR - 1;       h_cc = tid - 34; }
    else if (tid < 84)   { h_r = tid - 68 + 1; h_cc = 0; }
    else if (tid < NHALO){ h_r = tid - 84 + 1; h_cc = GC - 1; }
    const bool has_halo = (tid < NHALO);
    const bool h_in = !EDGE || (((unsigned)(ty0 - 1 + h_r) < HW) &&
                                ((unsigned)(tx0 - 1 + h_cc) < HW));
    const int  h_b  = h_r * HC + h_cc;            // s_blur read base
    const int  h_gw = h_r * GCP + h_cc;           // s_grad write

    f32x2 e_first = mk2(0.f, 0.f);
    float acc = 0.0f;

    for (int img = 0; img < 2; ++img) {
        const float* base = (img == 0) ? bA : bB;
        f32x2 gxs2 = mk2(0.f, 0.f), gys2 = mk2(0.f, 0.f), gms2 = mk2(0.f, 0.f);
        float hmag = 0.0f;

        for (int c = 0; c < 3; ++c) {
            const float* plane = base + c * (HW * HW);

            // ---- A1: horizontal 5-tap gaussian, 4 outputs/thread -> s_tmp
            // packed: sliding-window tap pairs -> v_pk_fma_f32 chains
            if (a1on) {
                float4 o = make_float4(0.f, 0.f, 0.f, 0.f);
                if (y1ok) {
                    const float4 a = *(const float4*)(plane + ga);
                    const float4 b = *(const float4*)(plane + gb);
                    const f32x2 p0 = mk2(a.x, a.y), p1 = mk2(a.y, a.z);
                    const f32x2 p2 = mk2(a.z, a.w), p3 = mk2(a.w, b.x);
                    const f32x2 p4 = mk2(b.x, b.y);
                    const f32x2 q3 = mk2(b.y, b.z), q4 = mk2(b.z, b.w);
                    const f32x2 oxy = g0p*p0 + g1p*p1 + g2p*p2 + g1p*p3 + g0p*p4;
                    const f32x2 ozw = g0p*p2 + g1p*p3 + g2p*p4 + g1p*q3 + g0p*q4;
                    o.x = oxy.x; o.y = oxy.y; o.z = ozw.x; o.w = ozw.y;
                    if (EDGE) {
                        if (x0 < 0) {             // left image edge (x0 == -4)
                            o.x = G0f*a.x;
                            o.y = G1f*a.x + G0f*a.y;
                            o.z = G2f*a.x + G1f*a.y + G0f*a.z;
                            o.w = G1f*a.x + G2f*a.y + G1f*a.z + G0f*a.w;
                        } else if (x0 > HW - 8) { // right image edge (x0 == 252)
                            o.x = G0f*a.x + G1f*a.y + G2f*a.z + G1f*a.w;
                            o.y = G0f*a.y + G1f*a.z + G2f*a.w;
                            o.z = G0f*a.z + G1f*a.w;
                            o.w = G0f*a.w;
                        }
                    }
                }
                *(float4*)&s_tmp[stw] = o;
            }
            __syncthreads();

            // ---- A2: vertical 5-tap gaussian, 4 outputs/thread -> s_blur
            // packed: (x,y) and (z,w) halves share tap positions exactly
            if (a2on) {
                float4 v = make_float4(0.f, 0.f, 0.f, 0.f);
                if (y2ok) {
                    const float4 t0 = *(const float4*)&s_tmp[stw];
                    const float4 t1 = *(const float4*)&s_tmp[stw + 1 * HC];
                    const float4 t2 = *(const float4*)&s_tmp[stw + 2 * HC];
                    const float4 t3 = *(const float4*)&s_tmp[stw + 3 * HC];
                    const float4 t4 = *(const float4*)&s_tmp[stw + 4 * HC];
                    const f32x2 vxy = g0p*mk2(t0.x,t0.y) + g1p*mk2(t1.x,t1.y)
                                    + g2p*mk2(t2.x,t2.y) + g1p*mk2(t3.x,t3.y)
                                    + g0p*mk2(t4.x,t4.y);
                    const f32x2 vzw = g0p*mk2(t0.z,t0.w) + g1p*mk2(t1.z,t1.w)
                                    + g2p*mk2(t2.z,t2.w) + g1p*mk2(t3.z,t3.w)
                                    + g0p*mk2(t4.z,t4.w);
                    v.x = ok0 ? vxy.x : 0.f;
                    v.y = ok1 ? vxy.y : 0.f;
                    v.z = ok2 ? vzw.x : 0.f;
                    v.w = ok3 ? vzw.y : 0.f;
                }
                *(float4*)&s_blur[stw] = v;
            }
            __syncthreads();

            // ---- A3a: interior sobel via row-sum factoring, packed over k=0,1
            {
                float cd[4], rs[4];
                #pragma unroll
                for (int r = 0; r < 4; ++r) {
                    const float* b = &s_blur[b3 + r * HC];
                    const float bl = b[0], bc = b[1], br = b[2];
                    cd[r] = bl - br;
                    rs[r] = bl + 2.0f * bc + br;
                }
                const f32x2 gx2 = mk2(cd[0], cd[1]) + 2.0f * mk2(cd[1], cd[2])
                                + mk2(cd[2], cd[3]);
                const f32x2 gy2 = mk2(rs[0], rs[1]) - mk2(rs[2], rs[3]);
                gxs2 += gx2;
                gys2 += gy2;
                const f32x2 m2 = gx2 * gx2 + gy2 * gy2;
                gms2 += mk2(fast_sqrtf(m2.x), fast_sqrtf(m2.y));
                s_grad[gw]       = gms2.x;
                s_grad[gw + GCP] = gms2.y;
            }

            // ---- A3b: halo sobel (perimeter of GR x GC), one elem per thread
            if (has_halo) {
                float gmag = 0.0f;
                if (h_in) {
                    const float* b = &s_blur[h_b];
                    const float b00 = b[0],        b01 = b[1],          b02 = b[2];
                    const float b10 = b[HC],                            b12 = b[HC + 2];
                    const float b20 = b[2 * HC],   b21 = b[2 * HC + 1], b22 = b[2 * HC + 2];
                    const float gx = (b00 + 2.0f * b10 + b20) - (b02 + 2.0f * b12 + b22);
                    const float gy = (b00 + 2.0f * b01 + b02) - (b20 + 2.0f * b21 + b22);
                    gmag = fast_sqrtf(gx * gx + gy * gy);
                }
                hmag += gmag;
                s_grad[h_gw] = hmag;
            }
            // no sync here: next A1 writes only s_tmp, whose readers (A2) are
            // fenced by the post-A2 sync; s_blur readers (A3) complete before
            // any thread passes the next post-A1 sync.
        }
        __syncthreads();  // s_grad complete for all channels

        // ---- Phase B: axis-based NMS + threshold at owned pixels
        f32x2 e2;
        #pragma unroll
        for (int k = 0; k < 2; ++k) {
            const float gc = (k == 0) ? gms2.x : gms2.y;
            const float gx = (k == 0) ? gxs2.x : gxs2.y;
            const float gy = (k == 0) ? gys2.x : gys2.y;
            const float ax = fabsf(gx), ay = fabsf(gy);
            int dy, dx;
            if (ay <= T1 * ax)      { dy = 0; dx = 1; }   // near 0/180 deg
            else if (ay >= T2 * ax) { dy = 1; dx = 0; }   // near +-90 deg
            else                    { dy = 1; dx = ((gx > 0.0f) == (gy > 0.0f)) ? 1 : -1; }
            const int ci = gw + k * GCP;
            const float pos = gc - s_grad[ci + dy * GCP + dx];
            const float neg = gc - s_grad[ci - dy * GCP - dx];
            const float thin = (fminf(pos, neg) > 0.0f) ? gc : 0.0f;
            const float e    = (thin < 2.0f) ? 0.0f : thin;
            if (k == 0) e2.x = e; else e2.y = e;
        }
        if (img == 0) e_first = e2;
        else          acc += fabsf(e2.x - e_first.x) + fabsf(e2.y - e_first.y);
        __syncthreads();  // s_grad reused by next image
    }
    return acc;
}

__global__ __launch_bounds__(256, 8)
void canny_tile_kernel(const float* __restrict__ imgA,
                       const float* __restrict__ imgB,
                       float* __restrict__ partials)
{
    __shared__ __align__(16) float s_tmp[BR * HC];   // horizontal gaussian
    __shared__ __align__(16) float s_blur[VR * HC];  // full blur
    __shared__ float s_grad[GR * GCP];               // channel-summed |grad| (padded stride)
    __shared__ float s_red[4];

    const int tid = threadIdx.x;
    // XCD-chunked bijective swizzle: xcd = blockIdx % 8 gets logical tiles
    // [xcd*1024, (xcd+1)*1024) -> neighbor tiles / same frame share an L2.
    const int bid = blockIdx.x;
    const int lg  = (bid & 7) * (NBLK / 8) + (bid >> 3);
    const int n    = lg >> 7;            // frame 0..63
    const int tile = lg & 127;
    const int rt   = tile >> 3;          // row-tile 0..15
    const int ct   = tile & 7;           // col-tile 0..7
    const int ty0  = rt * TR;
    const int tx0  = ct * TC;

    const float* bA = imgA + (size_t)n * 3 * (HW * HW);
    const float* bB = imgB + (size_t)n * 3 * (HW * HW);

    // interior: all staged rows/cols strictly inside the image
    const bool interior = (rt >= 1) && (rt <= 14) && (ct >= 1) && (ct <= 6);

    float acc;
    if (interior) acc = tile_body<false>(bA, bB, tid, ty0, tx0, s_tmp, s_blur, s_grad);
    else          acc = tile_body<true >(bA, bB, tid, ty0, tx0, s_tmp, s_blur, s_grad);

    // ---- deterministic block reduction
    #pragma unroll
    for (int off = 32; off > 0; off >>= 1) acc += __shfl_down(acc, off, 64);
    if ((tid & 63) == 0) s_red[tid >> 6] = acc;
    __syncthreads();
    if (tid == 0) partials[bid] = (s_red[0] + s_red[1]) + (s_red[2] + s_red[3]);
}

__global__ void final_reduce_kernel(const float* __restrict__ partials,
                                    float* __restrict__ out)
{
    __shared__ float s_red[16];
    const int tid = threadIdx.x;  // 1024 threads
    const float4 a = *(const float4*)&partials[4 * tid];
    const float4 b = *(const float4*)&partials[4 * tid + 4096];
    float v = ((a.x + a.y) + (a.z + a.w)) + ((b.x + b.y) + (b.z + b.w));
    #pragma unroll
    for (int off = 32; off > 0; off >>= 1) v += __shfl_down(v, off, 64);
    if ((tid & 63) == 0) s_red[tid >> 6] = v;
    __syncthreads();
    if (tid == 0) {
        float s = 0.0f;
        #pragma unroll
        for (int j = 0; j < 16; ++j) s += s_red[j];
        out[0] = s * (1.0f / 4194304.0f);
    }
}

extern "C" void kernel_launch(void* const* d_in, const int* in_sizes, int n_in,
                              void* d_out, int out_size, void* d_ws, size_t ws_size,
                              hipStream_t stream)
{
    const float* tgt     = (const float*)d_in[0];  // data_input  [4,16,3,256,256]
    const float* out_img = (const float*)d_in[1];  // model_output
    float* partials = (float*)d_ws;                // 8192 floats

    canny_tile_kernel<<<NBLK, 256, 0, stream>>>(out_img, tgt, partials);
    final_reduce_kernel<<<1, 1024, 0, stream>>>(partials, (float*)d_out);
}